// Round 1
// baseline (1034.066 us; speedup 1.0000x reference)
//
#include <hip/hip_runtime.h>
#include <cstdint>
#include <cstddef>

#define NN 100000
#define NE 1600000

__device__ __forceinline__ float4 f4_fma(float s, float4 a, float4 acc) {
    acc.x += s * a.x; acc.y += s * a.y; acc.z += s * a.z; acc.w += s * a.w;
    return acc;
}

// Detect edge_index storage: int64 (odd 32-bit words all zero, since values < 2^31)
// vs int32 (odd words are random node ids — practically never all zero).
__global__ void detect_flag_kernel(const int* __restrict__ idx, int* __restrict__ flag) {
    __shared__ int cnt;
    if (threadIdx.x == 0) cnt = 0;
    __syncthreads();
    if (idx[2 * threadIdx.x + 1] == 0) atomicAdd(&cnt, 1);
    __syncthreads();
    if (threadIdx.x == 0) *flag = (cnt == (int)blockDim.x) ? 1 : 0;
}

__global__ void extract_kernel(const void* __restrict__ idx, const int* __restrict__ flag,
                               int* __restrict__ src, int* __restrict__ dst) {
    int e = blockIdx.x * blockDim.x + threadIdx.x;
    if (e >= NE) return;
    if (*flag) {
        const long long* p = (const long long*)idx;
        src[e] = (int)p[e];
        dst[e] = (int)p[NE + e];
    } else {
        const int* p = (const int*)idx;
        src[e] = p[e];
        dst[e] = p[NE + e];
    }
}

__global__ void deg_kernel(const int* __restrict__ dst, int* __restrict__ deg) {
    int e = blockIdx.x * blockDim.x + threadIdx.x;
    if (e < NE) atomicAdd(&deg[dst[e]], 1);
}

__global__ void dinv_kernel(const int* __restrict__ deg, float* __restrict__ dinv) {
    int n = blockIdx.x * blockDim.x + threadIdx.x;
    if (n < NN) dinv[n] = rsqrtf((float)(deg[n] + 1));  // +1 self loop; deg>=1 always
}

// Single-block exclusive scan of deg -> row_start[0..NN], plus cursor copy.
__global__ __launch_bounds__(1024) void scan_kernel(const int* __restrict__ deg,
                                                    int* __restrict__ row_start,
                                                    int* __restrict__ cursor) {
    __shared__ int sums[1024];
    const int T = 1024;
    int t = threadIdx.x;
    const int chunk = (NN + T - 1) / T;  // 98
    int beg = t * chunk;
    int end = beg + chunk; if (end > NN) end = NN;
    int s = 0;
    for (int i = beg; i < end; i++) s += deg[i];
    sums[t] = s;
    __syncthreads();
    for (int off = 1; off < T; off <<= 1) {
        int v = (t >= off) ? sums[t - off] : 0;
        __syncthreads();
        sums[t] += v;
        __syncthreads();
    }
    int offset = (t == 0) ? 0 : sums[t - 1];
    for (int i = beg; i < end; i++) {
        row_start[i] = offset;
        cursor[i] = offset;
        offset += deg[i];
    }
    if (t == T - 1) row_start[NN] = sums[T - 1];  // == NE
}

__global__ void fill_kernel(const int* __restrict__ src, const int* __restrict__ dst,
                            int* __restrict__ cursor, int* __restrict__ csr) {
    int e = blockIdx.x * blockDim.x + threadIdx.x;
    if (e >= NE) return;
    int pos = atomicAdd(&cursor[dst[e]], 1);
    csr[pos] = src[e];
}

// H[N,F] = X[N,128] @ W[128,F]. fp32 vector-ALU GEMM, W staged in LDS.
template <int F>
__global__ __launch_bounds__(256) void gemm_kernel(const float* __restrict__ X,
                                                   const float* __restrict__ W,
                                                   float* __restrict__ H, int N) {
    constexpr int K = 128;
    constexpr int CQ = F / 4;        // col quads per row
    constexpr int RS = 256 / CQ;     // row slots per block
    constexpr int ROWS = RS * 4;     // rows per block
    __shared__ float Wlds[K * F];
    for (int i = threadIdx.x; i < K * F / 4; i += 256)
        ((float4*)Wlds)[i] = ((const float4*)W)[i];
    __syncthreads();

    int c = (threadIdx.x % CQ) * 4;
    int r0 = blockIdx.x * ROWS + (threadIdx.x / CQ) * 4;
    float4 acc[4];
#pragma unroll
    for (int i = 0; i < 4; i++) acc[i] = make_float4(0.f, 0.f, 0.f, 0.f);

    for (int k = 0; k < K; k += 4) {
        float4 xv[4];
#pragma unroll
        for (int i = 0; i < 4; i++) {
            int rr = r0 + i; if (rr >= N) rr = N - 1;
            xv[i] = *(const float4*)&X[(size_t)rr * K + k];
        }
#pragma unroll
        for (int j = 0; j < 4; j++) {
            float4 wv = *(const float4*)&Wlds[(k + j) * F + c];
#pragma unroll
            for (int i = 0; i < 4; i++) {
                float xk = ((const float*)&xv[i])[j];
                acc[i] = f4_fma(xk, wv, acc[i]);
            }
        }
    }
#pragma unroll
    for (int i = 0; i < 4; i++) {
        int rr = r0 + i;
        if (rr < N) *(float4*)&H[(size_t)rr * F + c] = acc[i];
    }
}

// OUT[n] = (relu?)( b + dinv[n]^2*H[n] + sum_e dinv[src]*dinv[n]*H[src] )
template <int F, bool RELU>
__global__ __launch_bounds__(256) void agg_kernel(const float* __restrict__ H,
                                                  const int* __restrict__ rs,
                                                  const int* __restrict__ csr,
                                                  const float* __restrict__ dinv,
                                                  const float* __restrict__ bias,
                                                  float* __restrict__ OUT) {
    constexpr int CQ = F / 4;
    constexpr int NPB = 256 / CQ;
    int node = blockIdx.x * NPB + threadIdx.x / CQ;
    int q = (threadIdx.x % CQ) * 4;
    if (node >= NN) return;
    float dn = dinv[node];
    float4 acc = *(const float4*)&bias[q];
    float4 h = *(const float4*)&H[(size_t)node * F + q];
    acc = f4_fma(dn * dn, h, acc);   // self loop
    int e1 = rs[node + 1];
    for (int e = rs[node]; e < e1; e++) {
        int s = csr[e];
        float w = dinv[s] * dn;
        float4 hv = *(const float4*)&H[(size_t)s * F + q];
        acc = f4_fma(w, hv, acc);
    }
    if (RELU) {
        acc.x = fmaxf(acc.x, 0.f); acc.y = fmaxf(acc.y, 0.f);
        acc.z = fmaxf(acc.z, 0.f); acc.w = fmaxf(acc.w, 0.f);
    }
    *(float4*)&OUT[(size_t)node * F + q] = acc;
}

extern "C" void kernel_launch(void* const* d_in, const int* in_sizes, int n_in,
                              void* d_out, int out_size, void* d_ws, size_t ws_size,
                              hipStream_t stream) {
    const float* x  = (const float*)d_in[0];
    const void* eidx = d_in[1];
    const float* W1 = (const float*)d_in[2];
    const float* b1 = (const float*)d_in[3];
    const float* W2 = (const float*)d_in[4];
    const float* b2 = (const float*)d_in[5];
    const float* W3 = (const float*)d_in[6];
    const float* b3 = (const float*)d_in[7];
    float* out = (float*)d_out;

    char* ws = (char*)d_ws;
    size_t off = 0;
    auto alloc = [&](size_t bytes) -> void* {
        void* p = ws + off;
        off += (bytes + 255) & ~(size_t)255;
        return p;
    };
    // bufB (51.2 MB) overlaps the CSR-build scratch (dead after fill_kernel)
    float* bufB = (float*)alloc((size_t)NN * 128 * 4);
    int* src32  = (int*)bufB;                                  // NE ints
    int* dst32  = (int*)((char*)bufB + (size_t)NE * 4);        // NE ints
    int* deg    = (int*)((char*)bufB + (size_t)2 * NE * 4);    // NN ints
    int* cursor = (int*)((char*)bufB + (size_t)2 * NE * 4 + (size_t)NN * 4);
    int* row_start = (int*)alloc((size_t)(NN + 1) * 4);
    float* dinv = (float*)alloc((size_t)NN * 4);
    int* flagp  = (int*)alloc(256);
    int* csr    = (int*)alloc((size_t)NE * 4);
    float* bufA = (float*)alloc((size_t)NN * 128 * 4);

    hipMemsetAsync(deg, 0, (size_t)NN * 4, stream);
    detect_flag_kernel<<<1, 256, 0, stream>>>((const int*)eidx, flagp);
    extract_kernel<<<NE / 256, 256, 0, stream>>>(eidx, flagp, src32, dst32);
    deg_kernel<<<NE / 256, 256, 0, stream>>>(dst32, deg);
    dinv_kernel<<<(NN + 255) / 256, 256, 0, stream>>>(deg, dinv);
    scan_kernel<<<1, 1024, 0, stream>>>(deg, row_start, cursor);
    fill_kernel<<<NE / 256, 256, 0, stream>>>(src32, dst32, cursor, csr);

    // Layer 1: h = x@W1 ; x2 = relu(agg + b1)
    gemm_kernel<128><<<NN / 32, 256, 0, stream>>>(x, W1, bufA, NN);
    agg_kernel<128, true><<<NN / 8, 256, 0, stream>>>(bufA, row_start, csr, dinv, b1, bufB);
    // Layer 2
    gemm_kernel<128><<<NN / 32, 256, 0, stream>>>(bufB, W2, bufA, NN);
    agg_kernel<128, true><<<NN / 8, 256, 0, stream>>>(bufA, row_start, csr, dinv, b2, bufB);
    // Layer 3 (128 -> 64, no relu)
    gemm_kernel<64><<<(NN + 63) / 64, 256, 0, stream>>>(bufB, W3, bufA, NN);
    agg_kernel<64, false><<<NN / 16, 256, 0, stream>>>(bufA, row_start, csr, dinv, b3, out);
}

// Round 2
// 791.391 us; speedup vs baseline: 1.3066x; 1.3066x over previous
//
#include <hip/hip_runtime.h>
#include <cstdint>
#include <cstddef>

#define NN 100000
#define NE 1600000
#define SCAN_BLOCKS ((NN + 1023) / 1024)   // 98

__device__ __forceinline__ float4 f4_fma(float s, float4 a, float4 acc) {
    acc.x += s * a.x; acc.y += s * a.y; acc.z += s * a.z; acc.w += s * a.w;
    return acc;
}
__device__ __forceinline__ float4 f4_add(float4 a, float4 b) {
    return make_float4(a.x + b.x, a.y + b.y, a.z + b.z, a.w + b.w);
}

// Detect edge_index storage: int64 (odd 32-bit words all zero, values < 2^31)
// vs int32 (odd words are random node ids).
__global__ void detect_flag_kernel(const int* __restrict__ idx, int* __restrict__ flag) {
    __shared__ int cnt;
    if (threadIdx.x == 0) cnt = 0;
    __syncthreads();
    if (idx[2 * threadIdx.x + 1] == 0) atomicAdd(&cnt, 1);
    __syncthreads();
    if (threadIdx.x == 0) *flag = (cnt == (int)blockDim.x) ? 1 : 0;
}

__global__ void extract_deg_kernel(const void* __restrict__ idx, const int* __restrict__ flag,
                                   int* __restrict__ src, int* __restrict__ dst,
                                   int* __restrict__ deg) {
    int e = blockIdx.x * blockDim.x + threadIdx.x;
    if (e >= NE) return;
    int s_, d_;
    if (*flag) {
        const long long* p = (const long long*)idx;
        s_ = (int)p[e]; d_ = (int)p[NE + e];
    } else {
        const int* p = (const int*)idx;
        s_ = p[e]; d_ = p[NE + e];
    }
    src[e] = s_; dst[e] = d_;
    atomicAdd(&deg[d_], 1);
}

__global__ void dinv_kernel(const int* __restrict__ deg, float* __restrict__ dinv) {
    int n = blockIdx.x * blockDim.x + threadIdx.x;
    if (n < NN) dinv[n] = rsqrtf((float)(deg[n] + 1));  // +1 self loop
}

// Hierarchical scan, pass 1: per-block (1024 elems) sums.
__global__ __launch_bounds__(256) void scanA_kernel(const int* __restrict__ deg,
                                                    int* __restrict__ blocksum) {
    __shared__ int red[256];
    int t = threadIdx.x;
    int base = blockIdx.x * 1024 + t * 4;
    int s = 0;
#pragma unroll
    for (int j = 0; j < 4; j++) { int i = base + j; if (i < NN) s += deg[i]; }
    red[t] = s;
    __syncthreads();
    for (int off = 128; off > 0; off >>= 1) {
        if (t < off) red[t] += red[t + off];
        __syncthreads();
    }
    if (t == 0) blocksum[blockIdx.x] = red[0];
}

// Pass 2: per-block exclusive scan + block offset; writes row_start and cursor.
__global__ __launch_bounds__(256) void scanC_kernel(const int* __restrict__ deg,
                                                    const int* __restrict__ blocksum,
                                                    int* __restrict__ row_start,
                                                    int* __restrict__ cursor) {
    __shared__ int lds[256];
    __shared__ int boff_s;
    int t = threadIdx.x;
    int b = blockIdx.x;
    // block offset = sum of blocksum[0..b-1]  (SCAN_BLOCKS=98 < 256)
    lds[t] = (t < b) ? blocksum[t] : 0;
    __syncthreads();
    for (int off = 128; off > 0; off >>= 1) {
        if (t < off) lds[t] += lds[t + off];
        __syncthreads();
    }
    if (t == 0) boff_s = lds[0];
    __syncthreads();
    int boff = boff_s;

    int base = b * 1024 + t * 4;
    int d[4]; int s = 0;
#pragma unroll
    for (int j = 0; j < 4; j++) { int i = base + j; d[j] = (i < NN) ? deg[i] : 0; s += d[j]; }
    __syncthreads();
    lds[t] = s;
    __syncthreads();
    for (int off = 1; off < 256; off <<= 1) {
        int u = (t >= off) ? lds[t - off] : 0;
        __syncthreads();
        lds[t] += u;
        __syncthreads();
    }
    int offr = boff + ((t == 0) ? 0 : lds[t - 1]);
#pragma unroll
    for (int j = 0; j < 4; j++) {
        int i = base + j;
        if (i < NN) { row_start[i] = offr; cursor[i] = offr; offr += d[j]; }
    }
    if (b == 0 && t == 0) row_start[NN] = NE;
}

__global__ void fill_kernel(const int* __restrict__ src, const int* __restrict__ dst,
                            int* __restrict__ cursor, int* __restrict__ csr) {
    int e = blockIdx.x * blockDim.x + threadIdx.x;
    if (e >= NE) return;
    int pos = atomicAdd(&cursor[dst[e]], 1);
    csr[pos] = src[e];
}

// H[N,F] = dinv[r] * (X[N,128] @ W[128,F]).  fp32 vector GEMM, W in LDS.
template <int F>
__global__ __launch_bounds__(256) void gemm_kernel(const float* __restrict__ X,
                                                   const float* __restrict__ W,
                                                   const float* __restrict__ dinv,
                                                   float* __restrict__ H, int N) {
    constexpr int K = 128;
    constexpr int CQ = F / 4;
    constexpr int RS = 256 / CQ;
    constexpr int ROWS = RS * 4;
    __shared__ float Wlds[K * F];
    for (int i = threadIdx.x; i < K * F / 4; i += 256)
        ((float4*)Wlds)[i] = ((const float4*)W)[i];
    __syncthreads();

    int c = (threadIdx.x % CQ) * 4;
    int r0 = blockIdx.x * ROWS + (threadIdx.x / CQ) * 4;
    float4 acc[4];
#pragma unroll
    for (int i = 0; i < 4; i++) acc[i] = make_float4(0.f, 0.f, 0.f, 0.f);

    for (int k = 0; k < K; k += 4) {
        float4 xv[4];
#pragma unroll
        for (int i = 0; i < 4; i++) {
            int rr = r0 + i; if (rr >= N) rr = N - 1;
            xv[i] = *(const float4*)&X[(size_t)rr * K + k];
        }
#pragma unroll
        for (int j = 0; j < 4; j++) {
            float4 wv = *(const float4*)&Wlds[(k + j) * F + c];
#pragma unroll
            for (int i = 0; i < 4; i++) {
                float xk = ((const float*)&xv[i])[j];
                acc[i] = f4_fma(xk, wv, acc[i]);
            }
        }
    }
#pragma unroll
    for (int i = 0; i < 4; i++) {
        int rr = r0 + i;
        if (rr < N) {
            float dv = dinv[rr];
            float4 o = make_float4(dv * acc[i].x, dv * acc[i].y, dv * acc[i].z, dv * acc[i].w);
            *(float4*)&H[(size_t)rr * F + c] = o;
        }
    }
}

// Hs is pre-scaled by dinv[row].  OUT[n] = (relu?)( b + dn * (Hs[n] + sum_e Hs[src]) )
template <int F, bool RELU>
__global__ __launch_bounds__(256) void agg_kernel(const float* __restrict__ Hs,
                                                  const int* __restrict__ rs,
                                                  const int* __restrict__ csr,
                                                  const float* __restrict__ dinv,
                                                  const float* __restrict__ bias,
                                                  float* __restrict__ OUT) {
    constexpr int CQ = F / 4;
    constexpr int NPB = 256 / CQ;
    int node = blockIdx.x * NPB + threadIdx.x / CQ;
    int q = (threadIdx.x % CQ) * 4;
    if (node >= NN) return;
    float dn = dinv[node];
    float4 acc = *(const float4*)&Hs[(size_t)node * F + q];  // self loop term
    int e = rs[node];
    int e1 = rs[node + 1];
    // unroll x4: 4 independent row-gathers in flight
    for (; e + 4 <= e1; e += 4) {
        int s0 = csr[e], s1 = csr[e + 1], s2 = csr[e + 2], s3 = csr[e + 3];
        float4 h0 = *(const float4*)&Hs[(size_t)s0 * F + q];
        float4 h1 = *(const float4*)&Hs[(size_t)s1 * F + q];
        float4 h2 = *(const float4*)&Hs[(size_t)s2 * F + q];
        float4 h3 = *(const float4*)&Hs[(size_t)s3 * F + q];
        acc = f4_add(acc, f4_add(f4_add(h0, h1), f4_add(h2, h3)));
    }
    for (; e < e1; e++) {
        int s = csr[e];
        acc = f4_add(acc, *(const float4*)&Hs[(size_t)s * F + q]);
    }
    float4 bv = *(const float4*)&bias[q];
    float4 o = f4_fma(dn, acc, bv);
    if (RELU) {
        o.x = fmaxf(o.x, 0.f); o.y = fmaxf(o.y, 0.f);
        o.z = fmaxf(o.z, 0.f); o.w = fmaxf(o.w, 0.f);
    }
    *(float4*)&OUT[(size_t)node * F + q] = o;
}

extern "C" void kernel_launch(void* const* d_in, const int* in_sizes, int n_in,
                              void* d_out, int out_size, void* d_ws, size_t ws_size,
                              hipStream_t stream) {
    const float* x  = (const float*)d_in[0];
    const void* eidx = d_in[1];
    const float* W1 = (const float*)d_in[2];
    const float* b1 = (const float*)d_in[3];
    const float* W2 = (const float*)d_in[4];
    const float* b2 = (const float*)d_in[5];
    const float* W3 = (const float*)d_in[6];
    const float* b3 = (const float*)d_in[7];
    float* out = (float*)d_out;

    char* ws = (char*)d_ws;
    size_t off = 0;
    auto alloc = [&](size_t bytes) -> void* {
        void* p = ws + off;
        off += (bytes + 255) & ~(size_t)255;
        return p;
    };
    // bufB (51.2 MB) overlaps CSR-build scratch (dead before agg1 writes bufB)
    float* bufB = (float*)alloc((size_t)NN * 128 * 4);
    int* src32  = (int*)bufB;                                  // NE ints
    int* dst32  = (int*)((char*)bufB + (size_t)NE * 4);        // NE ints
    int* deg    = (int*)((char*)bufB + (size_t)2 * NE * 4);    // NN ints
    int* cursor = (int*)((char*)bufB + (size_t)2 * NE * 4 + (size_t)NN * 4);
    int* blocksum  = (int*)((char*)bufB + (size_t)2 * NE * 4 + (size_t)2 * NN * 4);
    int* row_start = (int*)alloc((size_t)(NN + 1) * 4);
    float* dinv = (float*)alloc((size_t)NN * 4);
    int* flagp  = (int*)alloc(256);
    int* csr    = (int*)alloc((size_t)NE * 4);
    float* bufA = (float*)alloc((size_t)NN * 128 * 4);

    hipMemsetAsync(deg, 0, (size_t)NN * 4, stream);
    detect_flag_kernel<<<1, 256, 0, stream>>>((const int*)eidx, flagp);
    extract_deg_kernel<<<NE / 256, 256, 0, stream>>>(eidx, flagp, src32, dst32, deg);
    dinv_kernel<<<(NN + 255) / 256, 256, 0, stream>>>(deg, dinv);
    scanA_kernel<<<SCAN_BLOCKS, 256, 0, stream>>>(deg, blocksum);
    scanC_kernel<<<SCAN_BLOCKS, 256, 0, stream>>>(deg, blocksum, row_start, cursor);
    fill_kernel<<<NE / 256, 256, 0, stream>>>(src32, dst32, cursor, csr);

    // Layer 1
    gemm_kernel<128><<<NN / 32, 256, 0, stream>>>(x, W1, dinv, bufA, NN);
    agg_kernel<128, true><<<NN / 8, 256, 0, stream>>>(bufA, row_start, csr, dinv, b1, bufB);
    // Layer 2
    gemm_kernel<128><<<NN / 32, 256, 0, stream>>>(bufB, W2, dinv, bufA, NN);
    agg_kernel<128, true><<<NN / 8, 256, 0, stream>>>(bufA, row_start, csr, dinv, b2, bufB);
    // Layer 3 (128 -> 64, no relu)
    gemm_kernel<64><<<(NN + 63) / 64, 256, 0, stream>>>(bufB, W3, dinv, bufA, NN);
    agg_kernel<64, false><<<NN / 16, 256, 0, stream>>>(bufA, row_start, csr, dinv, b3, out);
}